// Round 3
// baseline (89.475 us; speedup 1.0000x reference)
//
#include <hip/hip_runtime.h>

// DetectionLayer (Mask R-CNN style) fused kernel for MI355X.
// B=8 images, one workgroup per image. N=1000 ROIs, C=81 classes.
// out: (B, 100, 6) float32 = [y1,x1,y2,x2,class_id,score]

#define NROI 1000
#define NCLS 81
#define MAXI 100
#define BLK  1024
#define MIN_CONF 0.7f
#define NMS_THR  0.3f

__global__ __launch_bounds__(BLK) void detection_kernel(
    const float* __restrict__ rois,    // B*N*4
    const float* __restrict__ probs,   // B*N*C
    const float* __restrict__ deltas,  // B*N*C*4
    const float* __restrict__ meta,    // B*meta_stride
    float* __restrict__ out,           // B*100*6
    int meta_stride)
{
  const int b   = blockIdx.x;
  const int tid = threadIdx.x;

  __shared__ float s_val[NROI];                       // unsorted score-or--1
  __shared__ float sy1[NROI], sx1[NROI], sy2[NROI], sx2[NROI]; // sorted boxes
  __shared__ float ssc[NROI];                         // sorted scores
  __shared__ int   scls[NROI];                        // sorted class ids
  __shared__ int   skeep[NROI];                       // keep flags (sorted order)
  __shared__ int   s_vcnt;                            // count of valid ROIs

  // ---- Phase 0: zero this image's output (d_out is poisoned, not re-poisoned)
  for (int k = tid; k < MAXI * 6; k += BLK)
    out[(size_t)b * (MAXI * 6) + k] = 0.0f;
  if (tid == 0) s_vcnt = 0;
  __syncthreads();

  // ---- Phase A: per-ROI argmax, delta-apply, clip, validity
  float score = -1.0f, y1 = 0.f, x1 = 0.f, y2 = 0.f, x2 = 0.f;
  int   cid = 0;
  if (tid < NROI) {
    const float* p = probs + ((size_t)b * NROI + tid) * NCLS;
    float best = p[0];
    int   bc = 0;
    for (int c = 1; c < NCLS; ++c) {
      float v = p[c];
      if (v > best) { best = v; bc = c; }   // strict > => first max (jnp.argmax)
    }
    cid = bc;

    const float* d  = deltas + (((size_t)b * NROI + tid) * NCLS + bc) * 4;
    float d0 = d[0] * 0.1f, d1 = d[1] * 0.1f;
    float d2 = d[2] * 0.2f, d3 = d[3] * 0.2f;

    const float* r = rois + ((size_t)b * NROI + tid) * 4;
    float ry1 = r[0], rx1 = r[1], ry2 = r[2], rx2 = r[3];
    float hh = ry2 - ry1, ww = rx2 - rx1;
    float cy = ry1 + 0.5f * hh + d0 * hh;
    float cx = rx1 + 0.5f * ww + d1 * ww;
    hh *= expf(d2);
    ww *= expf(d3);
    float ny1 = cy - 0.5f * hh, nx1 = cx - 0.5f * ww;
    float ny2 = cy + 0.5f * hh, nx2 = cx + 0.5f * ww;

    // window = (meta[b,7:11] - [0,0,1,1]) / ([h,w,h,w]-1), h/w from image 0
    float H  = meta[4], W = meta[5];       // image_meta[0, 4:7]
    float sy = H - 1.0f, sx = W - 1.0f;
    const float* m = meta + (size_t)b * meta_stride;
    float wy1 = m[7] / sy;
    float wx1 = m[8] / sx;
    float wy2 = (m[9]  - 1.0f) / sy;
    float wx2 = (m[10] - 1.0f) / sx;

    y1 = fminf(fmaxf(ny1, wy1), wy2);
    x1 = fminf(fmaxf(nx1, wx1), wx2);
    y2 = fminf(fmaxf(ny2, wy1), wy2);
    x2 = fminf(fmaxf(nx2, wx1), wx2);

    bool valid = (cid > 0) && (best >= MIN_CONF);
    score = valid ? best : -1.0f;
    s_val[tid] = score;
    if (valid) atomicAdd(&s_vcnt, 1);
  }
  __syncthreads();

  // ---- Phase B: stable descending rank (== jnp.argsort(-scores) stable),
  //      scatter into sorted arrays. Ranks are a bijection -> race-free.
  if (tid < NROI) {
    const float sv = score;
    int rnk = 0;
    for (int j = 0; j < NROI; ++j) {
      float o = s_val[j];
      if (o > sv || (o == sv && j < tid)) ++rnk;
    }
    ssc[rnk]  = score;
    sy1[rnk]  = y1;  sx1[rnk] = x1;  sy2[rnk] = y2;  sx2[rnk] = x2;
    scls[rnk] = cid;
    skeep[rnk] = (score > -0.5f) ? 1 : 0;
  }
  __syncthreads();

  // ---- Phase C: greedy NMS over sorted valid entries.
  // Thread j owns sorted slot j and is the ONLY writer of skeep[j].
  const int V = s_vcnt;   // valid entries occupy sorted slots [0, V)
  float jy1 = 0.f, jx1 = 0.f, jy2 = 0.f, jx2 = 0.f, jarea = 0.f;
  int   jcls = -1;
  if (tid < NROI) {
    jy1 = sy1[tid]; jx1 = sx1[tid]; jy2 = sy2[tid]; jx2 = sx2[tid];
    jarea = (jy2 - jy1) * (jx2 - jx1);
    jcls  = scls[tid];
  }
  volatile int* vkeep = skeep;
  int kc = 0;   // finalized-kept count; identical across threads (broadcast reads)
  for (int i = 0; i < V; ++i) {
    if (vkeep[i]) {                 // uniform: all threads read same LDS word
      ++kc;
      float by1 = sy1[i], bx1 = sx1[i], by2 = sy2[i], bx2 = sx2[i];
      int   bcls = scls[i];
      if (tid > i && tid < V && jcls == bcls && vkeep[tid]) {
        float barea = (by2 - by1) * (bx2 - bx1);
        float iy1 = fmaxf(by1, jy1), ix1 = fmaxf(bx1, jx1);
        float iy2 = fminf(by2, jy2), ix2 = fminf(bx2, jx2);
        float inter = fmaxf(iy2 - iy1, 0.f) * fmaxf(ix2 - ix1, 0.f);
        float uni   = barea + jarea - inter;
        float iou   = inter / fmaxf(uni, 1e-10f);
        if (iou > NMS_THR) skeep[tid] = 0;
      }
      __syncthreads();
      // Output = first MAXI kept entries in sorted order; once MAXI entries are
      // finalized-kept, later suppressions cannot change the output (identical
      // to full NMS + top_k, incl. stable tie-breaking).
      if (kc >= MAXI) break;
    }
    // vkeep[i]==0: no writes happened this iteration -> no barrier needed
  }
  __syncthreads();

  // ---- Phase D: compaction + emit
  if (tid < NROI && skeep[tid]) {
    int slot = 0;
    for (int q = 0; q < tid; ++q) slot += skeep[q];
    if (slot < MAXI) {
      float* o = out + ((size_t)b * MAXI + slot) * 6;
      o[0] = sy1[tid];
      o[1] = sx1[tid];
      o[2] = sy2[tid];
      o[3] = sx2[tid];
      o[4] = (float)scls[tid];
      o[5] = ssc[tid];
    }
  }
}

extern "C" void kernel_launch(void* const* d_in, const int* in_sizes, int n_in,
                              void* d_out, int out_size, void* d_ws, size_t ws_size,
                              hipStream_t stream) {
  const float* rois   = (const float*)d_in[0];
  const float* probs  = (const float*)d_in[1];
  const float* deltas = (const float*)d_in[2];
  const float* meta   = (const float*)d_in[3];
  float* out = (float*)d_out;

  const int nb = in_sizes[0] / (NROI * 4);       // = 8 images
  const int meta_stride = in_sizes[3] / nb;      // = 93 floats per image

  detection_kernel<<<nb, BLK, 0, stream>>>(rois, probs, deltas, meta, out,
                                           meta_stride);
}

// Round 4
// 55.853 us; speedup vs baseline: 1.6020x; 1.6020x over previous
//
#include <hip/hip_runtime.h>

// DetectionLayer (Mask R-CNN style) fused kernel for MI355X.
// B=8 images, one workgroup per image. N=1000 ROIs, C=81 classes.
// out: (B, 100, 6) float32 = [y1,x1,y2,x2,class_id,score]
//
// R3: bitonic key-sort (replaces O(N^2) rank scan, ~39us), ballot-scan
// compaction (replaces O(N) prefix loop). Exact stable argsort semantics via
// packed (inv_score, idx) uint64 keys.

#define NROI 1000
#define NCLS 81
#define MAXI 100
#define BLK  1024
#define MIN_CONF 0.7f
#define NMS_THR  0.3f

__global__ __launch_bounds__(BLK) void detection_kernel(
    const float* __restrict__ rois,    // B*N*4
    const float* __restrict__ probs,   // B*N*C
    const float* __restrict__ deltas,  // B*N*C*4
    const float* __restrict__ meta,    // B*meta_stride
    float* __restrict__ out,           // B*100*6
    int meta_stride)
{
  const int b   = blockIdx.x;
  const int tid = threadIdx.x;

  // unsorted per-ROI results
  __shared__ float u_y1[NROI], u_x1[NROI], u_y2[NROI], u_x2[NROI];
  __shared__ float u_sc[NROI];
  __shared__ int   u_cls[NROI];
  // sort keys
  __shared__ unsigned long long skey[BLK];
  // sorted arrays
  __shared__ float sy1[NROI], sx1[NROI], sy2[NROI], sx2[NROI];
  __shared__ float ssc[NROI];
  __shared__ int   scls[NROI];
  __shared__ int   skeep[NROI];
  __shared__ int   s_vcnt;
  __shared__ int   wcnt[BLK / 64];

  // ---- Phase 0: zero this image's output (d_out poisoned, not re-poisoned)
  for (int k = tid; k < MAXI * 6; k += BLK)
    out[(size_t)b * (MAXI * 6) + k] = 0.0f;
  if (tid == 0) s_vcnt = 0;

  // ---- Phase A: per-ROI argmax, delta-apply, clip, validity
  float score = -1.0f;
  if (tid < NROI) {
    const float* p = probs + ((size_t)b * NROI + tid) * NCLS;
    float best = p[0];
    int   bc = 0;
    for (int c = 1; c < NCLS; ++c) {
      float v = p[c];
      if (v > best) { best = v; bc = c; }   // strict > => first max (jnp.argmax)
    }

    const float* d  = deltas + (((size_t)b * NROI + tid) * NCLS + bc) * 4;
    float d0 = d[0] * 0.1f, d1 = d[1] * 0.1f;
    float d2 = d[2] * 0.2f, d3 = d[3] * 0.2f;

    const float* r = rois + ((size_t)b * NROI + tid) * 4;
    float ry1 = r[0], rx1 = r[1], ry2 = r[2], rx2 = r[3];
    float hh = ry2 - ry1, ww = rx2 - rx1;
    float cy = ry1 + 0.5f * hh + d0 * hh;
    float cx = rx1 + 0.5f * ww + d1 * ww;
    hh *= expf(d2);
    ww *= expf(d3);
    float ny1 = cy - 0.5f * hh, nx1 = cx - 0.5f * ww;
    float ny2 = cy + 0.5f * hh, nx2 = cx + 0.5f * ww;

    // window = (meta[b,7:11] - [0,0,1,1]) / ([h,w,h,w]-1), h/w from image 0
    float H  = meta[4], W = meta[5];       // image_meta[0, 4:7]
    float sy = H - 1.0f, sx = W - 1.0f;
    const float* m = meta + (size_t)b * meta_stride;
    float wy1 = m[7] / sy;
    float wx1 = m[8] / sx;
    float wy2 = (m[9]  - 1.0f) / sy;
    float wx2 = (m[10] - 1.0f) / sx;

    u_y1[tid] = fminf(fmaxf(ny1, wy1), wy2);
    u_x1[tid] = fminf(fmaxf(nx1, wx1), wx2);
    u_y2[tid] = fminf(fmaxf(ny2, wy1), wy2);
    u_x2[tid] = fminf(fmaxf(nx2, wx1), wx2);
    u_cls[tid] = bc;

    bool valid = (bc > 0) && (best >= MIN_CONF);
    score = valid ? best : -1.0f;
    u_sc[tid] = score;
    if (valid) atomicAdd(&s_vcnt, 1);
  }

  // ---- Phase B: bitonic sort of packed keys.
  // key = (~orderable(score) << 32) | idx  -> ascending sort == stable
  // descending argsort on score (ties -> lower idx first), exactly matching
  // jnp.argsort(-scores) with stable semantics.
  if (tid < NROI) {
    unsigned bits = __float_as_uint(score);
    unsigned ord  = (bits & 0x80000000u) ? ~bits : (bits | 0x80000000u);
    unsigned inv  = ~ord;                 // descending
    skey[tid] = ((unsigned long long)inv << 32) | (unsigned)tid;
  } else {
    skey[tid] = 0xFFFFFFFFFFFFFFFFull;    // padding sorts strictly last
  }
  __syncthreads();

  for (int k = 2; k <= BLK; k <<= 1) {
    for (int j = k >> 1; j > 0; j >>= 1) {
      int ixj = tid ^ j;
      if (ixj > tid) {
        unsigned long long a = skey[tid], c = skey[ixj];
        bool up = ((tid & k) == 0);
        if ((a > c) == up) { skey[tid] = c; skey[ixj] = a; }
      }
      __syncthreads();
    }
  }

  // gather payload into sorted order (ranks [NROI,BLK) hold padding keys)
  if (tid < NROI) {
    int oid = (int)(skey[tid] & 0xFFFFFFFFu);
    float sc = u_sc[oid];
    sy1[tid]  = u_y1[oid];  sx1[tid] = u_x1[oid];
    sy2[tid]  = u_y2[oid];  sx2[tid] = u_x2[oid];
    ssc[tid]  = sc;
    scls[tid] = u_cls[oid];
    skeep[tid] = (sc > -0.5f) ? 1 : 0;
  }
  __syncthreads();

  // ---- Phase C: greedy NMS over sorted valid entries.
  // Thread j owns sorted slot j and is the ONLY writer of skeep[j].
  const int V = s_vcnt;   // valid entries occupy sorted slots [0, V)
  float jy1 = 0.f, jx1 = 0.f, jy2 = 0.f, jx2 = 0.f, jarea = 0.f;
  int   jcls = -1;
  if (tid < NROI) {
    jy1 = sy1[tid]; jx1 = sx1[tid]; jy2 = sy2[tid]; jx2 = sx2[tid];
    jarea = (jy2 - jy1) * (jx2 - jx1);
    jcls  = scls[tid];
  }
  volatile int* vkeep = skeep;
  int kc = 0;   // finalized-kept count; uniform across threads (broadcast reads)
  for (int i = 0; i < V; ++i) {
    if (vkeep[i]) {                 // uniform broadcast read
      ++kc;
      float by1 = sy1[i], bx1 = sx1[i], by2 = sy2[i], bx2 = sx2[i];
      int   bcls = scls[i];
      if (tid > i && tid < V && jcls == bcls && vkeep[tid]) {
        float barea = (by2 - by1) * (bx2 - bx1);
        float iy1 = fmaxf(by1, jy1), ix1 = fmaxf(bx1, jx1);
        float iy2 = fminf(by2, jy2), ix2 = fminf(bx2, jx2);
        float inter = fmaxf(iy2 - iy1, 0.f) * fmaxf(ix2 - ix1, 0.f);
        float uni   = barea + jarea - inter;
        float iou   = inter / fmaxf(uni, 1e-10f);
        if (iou > NMS_THR) skeep[tid] = 0;
      }
      __syncthreads();
      // Output = first MAXI kept in sorted order; once MAXI are finalized,
      // later suppressions cannot change the output (== full NMS + top_k).
      if (kc >= MAXI) break;
    }
    // vkeep[i]==0: no writes this iteration -> no barrier needed
  }
  __syncthreads();

  // ---- Phase D: ballot-scan compaction + emit
  bool kept = (tid < NROI) && (skeep[tid] != 0);
  unsigned long long bm = __ballot(kept);
  int w = tid >> 6, lane = tid & 63;
  if (lane == 0) wcnt[w] = __popcll(bm);
  __syncthreads();
  if (kept) {
    int base = 0;
    for (int q = 0; q < w; ++q) base += wcnt[q];
    int slot = base + __popcll(bm & ((1ull << lane) - 1ull));
    if (slot < MAXI) {
      float* o = out + ((size_t)b * MAXI + slot) * 6;
      o[0] = sy1[tid];
      o[1] = sx1[tid];
      o[2] = sy2[tid];
      o[3] = sx2[tid];
      o[4] = (float)scls[tid];
      o[5] = ssc[tid];
    }
  }
}

extern "C" void kernel_launch(void* const* d_in, const int* in_sizes, int n_in,
                              void* d_out, int out_size, void* d_ws, size_t ws_size,
                              hipStream_t stream) {
  const float* rois   = (const float*)d_in[0];
  const float* probs  = (const float*)d_in[1];
  const float* deltas = (const float*)d_in[2];
  const float* meta   = (const float*)d_in[3];
  float* out = (float*)d_out;

  const int nb = in_sizes[0] / (NROI * 4);       // = 8 images
  const int meta_stride = in_sizes[3] / nb;      // = 93 floats per image

  detection_kernel<<<nb, BLK, 0, stream>>>(rois, probs, deltas, meta, out,
                                           meta_stride);
}

// Round 5
// 51.147 us; speedup vs baseline: 1.7494x; 1.0920x over previous
//
#include <hip/hip_runtime.h>

// DetectionLayer (Mask R-CNN style) fused kernel for MI355X.
// B=8 images, one workgroup per image. N=1000 ROIs, C=81 classes.
// out: (B, 100, 6) float32 = [y1,x1,y2,x2,class_id,score]
//
// R5: (1) hybrid bitonic sort — register keys, shfl_xor for j<64 (45 stages,
// 0 barriers), LDS only for j>=64 (10 stages); (2) chunked NMS — 64-entry
// chunks, per-thread 64-bit suppression-mask precompute (parallel IoU), then
// a register/ballot-only greedy resolve; 1 barrier/chunk instead of
// 1 barrier/kept-leader; (3) vectorized global loads (dwordx4 probs,
// float4 rois/deltas) and float4 LDS boxes.

#define NROI 1000
#define NCLS 81
#define MAXI 100
#define BLK  1024
#define NWAVE (BLK / 64)
#define MIN_CONF 0.7f
#define NMS_THR  0.3f

// 4-byte-aligned float4 for the 324B-strided prob rows (CDNA supports
// unaligned global dwordx4; worst case the compiler splits = old behavior).
typedef float f32x4u __attribute__((ext_vector_type(4), aligned(4)));

__device__ __forceinline__ unsigned long long shfl_xor_u64(unsigned long long v, int m) {
  unsigned lo = (unsigned)__shfl_xor((int)(unsigned)(v & 0xFFFFFFFFull), m, 64);
  unsigned hi = (unsigned)__shfl_xor((int)(unsigned)(v >> 32), m, 64);
  return (((unsigned long long)hi) << 32) | lo;
}

__global__ __launch_bounds__(BLK) void detection_kernel(
    const float* __restrict__ rois,    // B*N*4
    const float* __restrict__ probs,   // B*N*C
    const float* __restrict__ deltas,  // B*N*C*4
    const float* __restrict__ meta,    // B*meta_stride
    float* __restrict__ out,           // B*100*6
    int meta_stride)
{
  const int b    = blockIdx.x;
  const int tid  = threadIdx.x;
  const int lane = tid & 63;
  const int wv   = tid >> 6;

  __shared__ float4 u_box[NROI];                 // unsorted boxes
  __shared__ float  u_sc[NROI];
  __shared__ int    u_cls[NROI];
  __shared__ unsigned long long skey[BLK];       // bitonic LDS stages
  __shared__ float4 sbox[NROI];                  // sorted
  __shared__ float  ssc[NROI];
  __shared__ int    scls[NROI];
  __shared__ int    skeep[NROI];
  __shared__ int    s_vcnt;
  __shared__ int    wcnt[NWAVE];

  // ---- Phase 0: zero this image's output (d_out poisoned, not re-poisoned)
  for (int k = tid; k < MAXI * 6; k += BLK)
    out[(size_t)b * (MAXI * 6) + k] = 0.0f;
  if (tid == 0) s_vcnt = 0;     // ordered vs. readers by sort barriers

  // ---- Phase A: per-ROI argmax, delta-apply, clip, validity
  float score = -1.0f;
  if (tid < NROI) {
    const float* p = probs + ((size_t)b * NROI + tid) * NCLS;
    float best = p[0];
    int   bc = 0;
    for (int c0 = 1; c0 < NCLS; c0 += 4) {       // 81 = 1 + 20*4, exact
      f32x4u v = *(const f32x4u*)(p + c0);
#pragma unroll
      for (int e = 0; e < 4; ++e) {
        float f = v[e];
        if (f > best) { best = f; bc = c0 + e; } // strict > => first max
      }
    }

    const float4 dd = *(const float4*)(deltas + (((size_t)b * NROI + tid) * NCLS + bc) * 4);
    const float4 rr = *(const float4*)(rois + ((size_t)b * NROI + tid) * 4);

    float hh = rr.z - rr.x, ww = rr.w - rr.y;
    float cy = rr.x + 0.5f * hh + (dd.x * 0.1f) * hh;
    float cx = rr.y + 0.5f * ww + (dd.y * 0.1f) * ww;
    hh *= expf(dd.z * 0.2f);
    ww *= expf(dd.w * 0.2f);
    float ny1 = cy - 0.5f * hh, nx1 = cx - 0.5f * ww;
    float ny2 = cy + 0.5f * hh, nx2 = cx + 0.5f * ww;

    float H = meta[4], W = meta[5];              // image_meta[0, 4:7]
    float sy = H - 1.0f, sx = W - 1.0f;
    const float* m = meta + (size_t)b * meta_stride;
    float wy1 = m[7] / sy, wx1 = m[8] / sx;
    float wy2 = (m[9] - 1.0f) / sy, wx2 = (m[10] - 1.0f) / sx;

    float4 bb;
    bb.x = fminf(fmaxf(ny1, wy1), wy2);
    bb.y = fminf(fmaxf(nx1, wx1), wx2);
    bb.z = fminf(fmaxf(ny2, wy1), wy2);
    bb.w = fminf(fmaxf(nx2, wx1), wx2);
    u_box[tid] = bb;
    u_cls[tid] = bc;
    bool valid = (bc > 0) && (best >= MIN_CONF);
    score = valid ? best : -1.0f;
    u_sc[tid] = score;
  }

  // ---- Phase B: hybrid bitonic sort of packed keys (register-resident).
  // key = (~orderable(score) << 32) | idx: ascending sort == stable
  // descending argsort on score (ties -> lower idx), == jnp.argsort(-scores).
  unsigned long long key;
  if (tid < NROI) {
    unsigned bits = __float_as_uint(score);
    unsigned ord  = (bits & 0x80000000u) ? ~bits : (bits | 0x80000000u);
    key = (((unsigned long long)(~ord)) << 32) | (unsigned)tid;
  } else {
    key = 0xFFFFFFFFFFFFFFFFull;                 // padding sorts last
  }

  for (int k = 2; k <= BLK; k <<= 1) {
    for (int j = k >> 1; j > 0; j >>= 1) {
      const bool takeMin = (((tid & j) == 0) == ((tid & k) == 0));
      unsigned long long other;
      if (j >= 64) {                             // cross-wave: via LDS
        skey[tid] = key;
        __syncthreads();
        other = skey[tid ^ j];
        __syncthreads();                         // WAR for next stage
      } else {                                   // in-wave: via shfl_xor
        other = shfl_xor_u64(key, j);
      }
      const bool take = takeMin ? (other < key) : (other > key);
      key = take ? other : key;
    }
  }

  // gather payload into sorted order (key is in register; positions >= NROI
  // hold padding). Phase-A u_* writes are fenced by the sort barriers.
  if (tid < NROI) {
    int oid = (int)(key & 0xFFFFFFFFull);
    float sc = u_sc[oid];
    sbox[tid]  = u_box[oid];
    ssc[tid]   = sc;
    scls[tid]  = u_cls[oid];
    skeep[tid] = (sc > -0.5f) ? 1 : 0;
  }
  __syncthreads();

  // V = valid count = position of the single valid->invalid boundary
  if (tid < NROI) {
    bool v0 = ssc[tid] > -0.5f;
    bool v1 = (tid + 1 < NROI) ? (ssc[tid + 1] > -0.5f) : false;
    if (v0 && !v1) s_vcnt = tid + 1;             // unique writer
  }
  __syncthreads();
  const int V = s_vcnt;

  // ---- Phase C: chunked greedy NMS (exactly == sequential greedy order).
  bool   mykeep = false;
  float4 jb = make_float4(0.f, 0.f, 0.f, 0.f);
  float  jarea = 0.f;
  int    jcls = -1;
  if (tid < NROI) {
    jb = sbox[tid];
    jcls = scls[tid];
    jarea = (jb.z - jb.x) * (jb.w - jb.y);
    mykeep = skeep[tid] != 0;
  }

  int kc = 0;
  const int nchunks = (V + 63) >> 6;
  for (int c = 0; c < nchunks; ++c) {
    const int base = c << 6;
    // every wave mirrors the chunk: lane l <-> sorted entry base+l
    const int ce = base + lane;
    float4 cb = make_float4(0.f, 0.f, 0.f, 0.f);
    int  ccls = -1;
    bool ckeep = false;
    if (ce < NROI) {
      cb = sbox[ce];
      ccls = scls[ce];
      ckeep = skeep[ce] != 0;                    // includes prior-chunk kills
    }
    const float carea = (cb.z - cb.x) * (cb.w - cb.y);

    // parallel precompute of suppression masks (leader data = LDS broadcast)
    unsigned long long esup = 0ull;              // chunk-entry vs earlier entry
    unsigned long long jsup = 0ull;              // my slot vs chunk entry
    const bool doj = (wv > c) && mykeep;
#pragma unroll 8
    for (int l = 0; l < 64; ++l) {
      int li = base + l; if (li >= NROI) li = NROI - 1;   // clamp (dead anyway)
      const float4 lb = sbox[li];
      const int  lcls = scls[li];
      const float la  = (lb.z - lb.x) * (lb.w - lb.y);
      if (lane > l && ccls == lcls) {
        float iy1 = fmaxf(lb.x, cb.x), ix1 = fmaxf(lb.y, cb.y);
        float iy2 = fminf(lb.z, cb.z), ix2 = fminf(lb.w, cb.w);
        float inter = fmaxf(iy2 - iy1, 0.f) * fmaxf(ix2 - ix1, 0.f);
        if (inter > NMS_THR * fmaxf(la + carea - inter, 1e-10f)) esup |= (1ull << l);
      }
      if (doj && jcls == lcls) {
        float iy1 = fmaxf(lb.x, jb.x), ix1 = fmaxf(lb.y, jb.y);
        float iy2 = fminf(lb.z, jb.z), ix2 = fminf(lb.w, jb.w);
        float inter = fmaxf(iy2 - iy1, 0.f) * fmaxf(ix2 - ix1, 0.f);
        if (inter > NMS_THR * fmaxf(la + jarea - inter, 1e-10f)) jsup |= (1ull << l);
      }
    }

    // sequential greedy resolve: pure register/ballot chain, identical in
    // every wave (same chunk data => same alive mask).
    unsigned long long alive = __ballot(ckeep);
    for (int l = 0; l < 64; ++l) {
      if ((alive >> l) & 1ull) {
        unsigned long long kill = __ballot((int)((esup >> l) & 1ull));
        alive &= ~kill;                          // esup bits only at m > l
      }
    }

    if (wv == c) {                               // my slot IS chunk entry lane
      mykeep = ((alive >> (unsigned)lane) & 1ull) != 0;
      if (tid < NROI) skeep[tid] = mykeep ? 1 : 0;
    } else if (wv > c) {                         // suppressed by any kept leader
      if (jsup & alive) mykeep = false;
      if (tid < NROI) skeep[tid] = mykeep ? 1 : 0;
    }

    kc += (int)__popcll(alive);
    __syncthreads();                             // skeep visible to next chunk
    // Output = first MAXI kept in sorted order; once MAXI are finalized,
    // later suppressions cannot change the output (== full NMS + top_k).
    if (kc >= MAXI) break;
  }

  // ---- Phase D: ballot-scan compaction + emit.
  // Threads in unprocessed chunks may have stale mykeep=1, but their prefix
  // already contains >= MAXI kept => slot >= MAXI => filtered.
  unsigned long long bm = __ballot((int)mykeep);
  if (lane == 0) wcnt[wv] = (int)__popcll(bm);
  __syncthreads();
  if (mykeep) {
    int base2 = 0;
    for (int q = 0; q < wv; ++q) base2 += wcnt[q];
    int slot = base2 + (int)__popcll(bm & ((1ull << (unsigned)lane) - 1ull));
    if (slot < MAXI) {
      float4 bb = sbox[tid];                     // own earlier write
      float* o = out + ((size_t)b * MAXI + slot) * 6;
      o[0] = bb.x; o[1] = bb.y; o[2] = bb.z; o[3] = bb.w;
      o[4] = (float)scls[tid];
      o[5] = ssc[tid];
    }
  }
}

extern "C" void kernel_launch(void* const* d_in, const int* in_sizes, int n_in,
                              void* d_out, int out_size, void* d_ws, size_t ws_size,
                              hipStream_t stream) {
  const float* rois   = (const float*)d_in[0];
  const float* probs  = (const float*)d_in[1];
  const float* deltas = (const float*)d_in[2];
  const float* meta   = (const float*)d_in[3];
  float* out = (float*)d_out;

  const int nb = in_sizes[0] / (NROI * 4);       // = 8 images
  const int meta_stride = in_sizes[3] / nb;      // = 93 floats per image

  detection_kernel<<<nb, BLK, 0, stream>>>(rois, probs, deltas, meta, out,
                                           meta_stride);
}

// Round 6
// 38.158 us; speedup vs baseline: 2.3448x; 1.3404x over previous
//
#include <hip/hip_runtime.h>

// DetectionLayer (Mask R-CNN style), MI355X. B=8, N=1000 ROIs, C=81.
// out: (B, 100, 6) float32 = [y1,x1,y2,x2,class_id,score]
//
// R6: two-kernel split.
//  k1 refine_kernel (128 blocks x 64thr): per-ROI argmax/delta/clip -> d_ws.
//     Moves the scattered prob loads + argmax off the 8-CU critical path.
//  k2 sortnms_kernel (8 blocks x 1024thr): hybrid bitonic sort + chunked NMS.
//     NMS broadcasts chunk entries via v_readlane (VALU pipe) instead of LDS
//     broadcast reads (single shared LDS pipe was the R5 bottleneck);
//     single jsup mask per thread (wave c's esup == jsup with l<lane);
//     alive mask published via s_alive[chunk]; skeep LDS array removed.

#define NROI 1000
#define NCLS 81
#define MAXI 100
#define PAD  1024            // per-image slab stride in workspace
#define BLK  1024
#define MIN_CONF 0.7f
#define NMS_THR  0.3f

typedef float f32x4u __attribute__((ext_vector_type(4), aligned(4)));
typedef unsigned long long u64;

__device__ __forceinline__ u64 shfl_xor_u64(u64 v, int m) {
  unsigned lo = (unsigned)__shfl_xor((int)(unsigned)(v & 0xFFFFFFFFull), m, 64);
  unsigned hi = (unsigned)__shfl_xor((int)(unsigned)(v >> 32), m, 64);
  return (((u64)hi) << 32) | lo;
}
__device__ __forceinline__ float rl_f(float v, int l) {
  return __uint_as_float((unsigned)__builtin_amdgcn_readlane((int)__float_as_uint(v), l));
}
__device__ __forceinline__ int rl_i(int v, int l) {
  return __builtin_amdgcn_readlane(v, l);
}

// ---------------- kernel 1: per-ROI refine (widely parallel) ----------------
__global__ __launch_bounds__(64) void refine_kernel(
    const float* __restrict__ rois,    // B*N*4
    const float* __restrict__ probs,   // B*N*C
    const float* __restrict__ deltas,  // B*N*C*4
    const float* __restrict__ meta,    // B*meta_stride
    float4* __restrict__ ws_box,       // [B*PAD]
    float2* __restrict__ ws_aux,       // [B*PAD]  (score, cls)
    int meta_stride)
{
  const int b   = blockIdx.x >> 4;                  // 16 blocks per image
  const int roi = ((blockIdx.x & 15) << 6) + threadIdx.x;
  if (roi >= NROI) return;

  const float* p = probs + ((size_t)b * NROI + roi) * NCLS;
  float best = p[0];
  int   bc = 0;
  for (int c0 = 1; c0 < NCLS; c0 += 4) {            // 81 = 1 + 20*4, exact
    f32x4u v = *(const f32x4u*)(p + c0);
#pragma unroll
    for (int e = 0; e < 4; ++e) {
      float f = v[e];
      if (f > best) { best = f; bc = c0 + e; }      // strict > => first max
    }
  }

  const float4 dd = *(const float4*)(deltas + (((size_t)b * NROI + roi) * NCLS + bc) * 4);
  const float4 rr = *(const float4*)(rois + ((size_t)b * NROI + roi) * 4);

  float hh = rr.z - rr.x, ww = rr.w - rr.y;
  float cy = rr.x + 0.5f * hh + (dd.x * 0.1f) * hh;
  float cx = rr.y + 0.5f * ww + (dd.y * 0.1f) * ww;
  hh *= expf(dd.z * 0.2f);
  ww *= expf(dd.w * 0.2f);
  float ny1 = cy - 0.5f * hh, nx1 = cx - 0.5f * ww;
  float ny2 = cy + 0.5f * hh, nx2 = cx + 0.5f * ww;

  float H = meta[4], W = meta[5];                   // image_meta[0, 4:7]
  float sy = H - 1.0f, sx = W - 1.0f;
  const float* m = meta + (size_t)b * meta_stride;
  float wy1 = m[7] / sy, wx1 = m[8] / sx;
  float wy2 = (m[9] - 1.0f) / sy, wx2 = (m[10] - 1.0f) / sx;

  float4 bb;
  bb.x = fminf(fmaxf(ny1, wy1), wy2);
  bb.y = fminf(fmaxf(nx1, wx1), wx2);
  bb.z = fminf(fmaxf(ny2, wy1), wy2);
  bb.w = fminf(fmaxf(nx2, wx1), wx2);

  bool valid = (bc > 0) && (best >= MIN_CONF);
  float score = valid ? best : -1.0f;

  ws_box[(size_t)b * PAD + roi] = bb;
  ws_aux[(size_t)b * PAD + roi] = make_float2(score, (float)bc);
}

// ---------------- kernel 2: sort + NMS + emit (one block per image) ---------
__global__ __launch_bounds__(BLK) void sortnms_kernel(
    const float4* __restrict__ ws_box,
    const float2* __restrict__ ws_aux,
    float* __restrict__ out)
{
  const int b    = blockIdx.x;
  const int tid  = threadIdx.x;
  const int lane = tid & 63;
  const int wv   = tid >> 6;

  __shared__ u64    skey[BLK];          // bitonic LDS stages
  __shared__ float4 sbox[NROI];         // sorted boxes
  __shared__ float  ssc[NROI];          // sorted scores
  __shared__ int    scls[NROI];         // sorted class ids
  __shared__ u64    s_alive[BLK / 64];  // per-chunk final alive mask
  __shared__ int    wcnt[BLK / 64];
  __shared__ int    s_vcnt;

  // ---- zero this image's output (d_out poisoned, not re-poisoned)
  for (int k = tid; k < MAXI * 6; k += BLK)
    out[(size_t)b * (MAXI * 6) + k] = 0.0f;
  if (tid == 0) s_vcnt = 0;             // ordered vs readers by sort barriers

  // ---- build sort key from ws (coalesced 8B read)
  // key = (~orderable(score) << 32) | idx: ascending == stable descending
  // argsort on score (ties -> lower idx), == jnp.argsort(-scores).
  u64 key;
  if (tid < NROI) {
    float sc = ws_aux[(size_t)b * PAD + tid].x;
    unsigned bits = __float_as_uint(sc);
    unsigned ord  = (bits & 0x80000000u) ? ~bits : (bits | 0x80000000u);
    key = (((u64)(~ord)) << 32) | (unsigned)tid;
  } else {
    key = 0xFFFFFFFFFFFFFFFFull;        // padding sorts last
  }

  // ---- hybrid bitonic: shfl_xor for j<64 (no barriers), LDS for j>=64
  for (int k = 2; k <= BLK; k <<= 1) {
    for (int j = k >> 1; j > 0; j >>= 1) {
      const bool takeMin = (((tid & j) == 0) == ((tid & k) == 0));
      u64 other;
      if (j >= 64) {
        skey[tid] = key;
        __syncthreads();
        other = skey[tid ^ j];
        __syncthreads();                // WAR for next stage
      } else {
        other = shfl_xor_u64(key, j);
      }
      const bool take = takeMin ? (other < key) : (other > key);
      key = take ? other : key;
    }
  }

  // ---- gather payload into sorted order (global ws is L1/L2-hot)
  if (tid < NROI) {
    int oid = (int)(key & 0xFFFFFFFFull);
    float2 a = ws_aux[(size_t)b * PAD + oid];
    sbox[tid] = ws_box[(size_t)b * PAD + oid];
    ssc[tid]  = a.x;
    scls[tid] = (int)a.y;
  }
  __syncthreads();

  // V = valid count = the single valid->invalid boundary (unique writer)
  if (tid < NROI) {
    bool v0 = ssc[tid] > -0.5f;
    bool v1 = (tid + 1 < NROI) ? (ssc[tid + 1] > -0.5f) : false;
    if (v0 && !v1) s_vcnt = tid + 1;
  }
  __syncthreads();
  const int V = s_vcnt;

  // ---- chunked greedy NMS (exactly == sequential greedy order)
  bool   mykeep = false;
  float4 jb = make_float4(0.f, 0.f, 0.f, 0.f);
  float  jarea = 0.f;
  int    jcls = -1;
  if (tid < NROI) {
    jb = sbox[tid];
    jcls = scls[tid];
    jarea = (jb.z - jb.x) * (jb.w - jb.y);
    mykeep = ssc[tid] > -0.5f;
  }

  int kc = 0;
  const int nchunks = (V + 63) >> 6;
  for (int c = 0; c < nchunks; ++c) {
    const int base = c << 6;
    // lane <-> chunk entry; single LDS read per chunk, then register bcast
    int cei = base + lane; if (cei >= NROI) cei = NROI - 1;  // dead anyway
    const float4 cb   = sbox[cei];
    const int    ccls = scls[cei];
    const float  carea = (cb.z - cb.x) * (cb.w - cb.y);

    // jsup bit l: my entry is suppressed by chunk entry l (if l kept).
    // For wave c this doubles as esup (ordering via l < lane).
    u64 jsup = 0ull;
    if (mykeep && wv >= c) {
#pragma unroll 8
      for (int l = 0; l < 64; ++l) {
        float ly1 = rl_f(cb.x, l), lx1 = rl_f(cb.y, l);
        float ly2 = rl_f(cb.z, l), lx2 = rl_f(cb.w, l);
        float la  = rl_f(carea, l);
        int  lcls = rl_i(ccls, l);
        if ((wv > c || l < lane) && jcls == lcls) {
          float iy1 = fmaxf(ly1, jb.x), ix1 = fmaxf(lx1, jb.y);
          float iy2 = fminf(ly2, jb.z), ix2 = fminf(lx2, jb.w);
          float inter = fmaxf(iy2 - iy1, 0.f) * fmaxf(ix2 - ix1, 0.f);
          if (inter > NMS_THR * fmaxf(la + jarea - inter, 1e-10f))
            jsup |= (1ull << l);
        }
      }
    }

    if (wv == c) {                      // resolve greedy within own wave
      u64 aliveW = __ballot(mykeep);
      for (int l = 0; l < 64; ++l) {
        if ((aliveW >> l) & 1ull) {
          u64 kill = __ballot((int)((jsup >> l) & 1ull));
          aliveW &= ~kill;              // jsup bits only at lanes > l here
        }
      }
      mykeep = ((aliveW >> (unsigned)lane) & 1ull) != 0;
      if (lane == 0) s_alive[c] = aliveW;
    }
    __syncthreads();
    const u64 alive = s_alive[c];
    if (wv > c && (jsup & alive)) mykeep = false;
    kc += (int)__popcll(alive);
    // Output = first MAXI kept in sorted order; once MAXI are finalized,
    // later suppressions cannot change the output (== full NMS + top_k).
    if (kc >= MAXI) break;
  }

  // ---- ballot-scan compaction + emit.
  // Stale mykeep=1 threads (unprocessed chunks) get slot >= kc >= MAXI.
  u64 bm = __ballot((int)mykeep);
  if (lane == 0) wcnt[wv] = (int)__popcll(bm);
  __syncthreads();
  if (mykeep) {
    int base2 = 0;
    for (int q = 0; q < wv; ++q) base2 += wcnt[q];
    int slot = base2 + (int)__popcll(bm & ((1ull << (unsigned)lane) - 1ull));
    if (slot < MAXI) {
      float* o = out + ((size_t)b * MAXI + slot) * 6;
      o[0] = jb.x; o[1] = jb.y; o[2] = jb.z; o[3] = jb.w;
      o[4] = (float)jcls;
      o[5] = ssc[tid];
    }
  }
}

extern "C" void kernel_launch(void* const* d_in, const int* in_sizes, int n_in,
                              void* d_out, int out_size, void* d_ws, size_t ws_size,
                              hipStream_t stream) {
  const float* rois   = (const float*)d_in[0];
  const float* probs  = (const float*)d_in[1];
  const float* deltas = (const float*)d_in[2];
  const float* meta   = (const float*)d_in[3];
  float* out = (float*)d_out;

  const int nb = in_sizes[0] / (NROI * 4);       // = 8 images
  const int meta_stride = in_sizes[3] / nb;      // = 93 floats per image

  float4* ws_box = (float4*)d_ws;                              // nb*PAD*16 B
  float2* ws_aux = (float2*)((char*)d_ws + (size_t)nb * PAD * sizeof(float4));

  refine_kernel<<<nb * 16, 64, 0, stream>>>(rois, probs, deltas, meta,
                                            ws_box, ws_aux, meta_stride);
  sortnms_kernel<<<nb, BLK, 0, stream>>>(ws_box, ws_aux, out);
}

// Round 7
// 26.426 us; speedup vs baseline: 3.3859x; 1.4440x over previous
//
#include <hip/hip_runtime.h>

// DetectionLayer (Mask R-CNN style), MI355X. B=8, N=1000 ROIs, C=81.
// out: (B, 100, 6) float32 = [y1,x1,y2,x2,class_id,score]
//
// R7: (1) valid-compaction before the bitonic sort -> sort P=next_pow2(V)
// instead of 1024 (halves the u64-shuffle LDS traffic when V~500);
// (2) class-masked NMS: per chunk, leaders atomicOr a lane-bit into
// cmask[class]; each thread IoU-tests ONLY same-class leaders (set-bit
// iteration, ~1-2 tests vs 64). Greedy resolve iterates set bits too.

#define NROI 1000
#define NCLS 81
#define MAXI 100
#define PAD  1024            // per-image slab stride in workspace
#define BLK  1024
#define NW   (BLK / 64)
#define MIN_CONF 0.7f
#define NMS_THR  0.3f

typedef float f32x4u __attribute__((ext_vector_type(4), aligned(4)));
typedef unsigned long long u64;

__device__ __forceinline__ u64 shfl_xor_u64(u64 v, int m) {
  unsigned lo = (unsigned)__shfl_xor((int)(unsigned)(v & 0xFFFFFFFFull), m, 64);
  unsigned hi = (unsigned)__shfl_xor((int)(unsigned)(v >> 32), m, 64);
  return (((u64)hi) << 32) | lo;
}

// ---------------- kernel 1: per-ROI refine (widely parallel) ----------------
__global__ __launch_bounds__(64) void refine_kernel(
    const float* __restrict__ rois,    // B*N*4
    const float* __restrict__ probs,   // B*N*C
    const float* __restrict__ deltas,  // B*N*C*4
    const float* __restrict__ meta,    // B*meta_stride
    float4* __restrict__ ws_box,       // [B*PAD]
    float2* __restrict__ ws_aux,       // [B*PAD]  (score, cls)
    int meta_stride)
{
  const int b   = blockIdx.x >> 4;                  // 16 blocks per image
  const int roi = ((blockIdx.x & 15) << 6) + threadIdx.x;
  if (roi >= NROI) return;

  const float* p = probs + ((size_t)b * NROI + roi) * NCLS;
  float best = p[0];
  int   bc = 0;
  for (int c0 = 1; c0 < NCLS; c0 += 4) {            // 81 = 1 + 20*4, exact
    f32x4u v = *(const f32x4u*)(p + c0);
#pragma unroll
    for (int e = 0; e < 4; ++e) {
      float f = v[e];
      if (f > best) { best = f; bc = c0 + e; }      // strict > => first max
    }
  }

  const float4 dd = *(const float4*)(deltas + (((size_t)b * NROI + roi) * NCLS + bc) * 4);
  const float4 rr = *(const float4*)(rois + ((size_t)b * NROI + roi) * 4);

  float hh = rr.z - rr.x, ww = rr.w - rr.y;
  float cy = rr.x + 0.5f * hh + (dd.x * 0.1f) * hh;
  float cx = rr.y + 0.5f * ww + (dd.y * 0.1f) * ww;
  hh *= expf(dd.z * 0.2f);
  ww *= expf(dd.w * 0.2f);
  float ny1 = cy - 0.5f * hh, nx1 = cx - 0.5f * ww;
  float ny2 = cy + 0.5f * hh, nx2 = cx + 0.5f * ww;

  float H = meta[4], W = meta[5];                   // image_meta[0, 4:7]
  float sy = H - 1.0f, sx = W - 1.0f;
  const float* m = meta + (size_t)b * meta_stride;
  float wy1 = m[7] / sy, wx1 = m[8] / sx;
  float wy2 = (m[9] - 1.0f) / sy, wx2 = (m[10] - 1.0f) / sx;

  float4 bb;
  bb.x = fminf(fmaxf(ny1, wy1), wy2);
  bb.y = fminf(fmaxf(nx1, wx1), wx2);
  bb.z = fminf(fmaxf(ny2, wy1), wy2);
  bb.w = fminf(fmaxf(nx2, wx1), wx2);

  bool valid = (bc > 0) && (best >= MIN_CONF);
  float score = valid ? best : -1.0f;

  ws_box[(size_t)b * PAD + roi] = bb;
  ws_aux[(size_t)b * PAD + roi] = make_float2(score, (float)bc);
}

// ---------------- kernel 2: sort + NMS + emit (one block per image) ---------
__global__ __launch_bounds__(BLK) void sortnms_kernel(
    const float4* __restrict__ ws_box,
    const float2* __restrict__ ws_aux,
    float* __restrict__ out)
{
  const int b    = blockIdx.x;
  const int tid  = threadIdx.x;
  const int lane = tid & 63;
  const int wv   = tid >> 6;

  __shared__ u64    skey[BLK];          // compacted keys / bitonic LDS stages
  __shared__ float4 sbox[NROI];         // sorted valid boxes ([0,V) used)
  __shared__ float  ssc[NROI];
  __shared__ int    scls[NROI];
  __shared__ u64    cmask[NCLS];        // per-chunk class -> leader-lane mask
  __shared__ u64    s_alive;            // chunk resolve result
  __shared__ int    wcnt[NW];

  // ---- zero this image's output (d_out poisoned, not re-poisoned)
  for (int k = tid; k < MAXI * 6; k += BLK)
    out[(size_t)b * (MAXI * 6) + k] = 0.0f;

  // ---- load score, pad keys
  float sc = (tid < NROI) ? ws_aux[(size_t)b * PAD + tid].x : -1.0f;
  const bool valid = sc > -0.5f;
  skey[tid] = 0xFFFFFFFFFFFFFFFFull;    // padding sorts last

  // ---- stable compaction of valid entries (order-preserving in tid)
  u64 vb = __ballot(valid);
  if (lane == 0) wcnt[wv] = (int)__popcll(vb);
  __syncthreads();                      // wcnt ready; skey pad visible
  int V = 0, cbase0 = 0;
  for (int w = 0; w < NW; ++w) {
    int c = wcnt[w];
    if (w < wv) cbase0 += c;
    V += c;
  }
  if (valid) {
    int slot = cbase0 + (int)__popcll(vb & ((1ull << (unsigned)lane) - 1ull));
    unsigned bits = __float_as_uint(sc);
    unsigned ord  = (bits & 0x80000000u) ? ~bits : (bits | 0x80000000u);
    // key = (~orderable(score) << 32) | orig_idx: ascending == stable
    // descending argsort on score (ties -> lower orig idx).
    skey[slot] = (((u64)(~ord)) << 32) | (unsigned)tid;
  }
  __syncthreads();

  // ---- hybrid bitonic sort of P = next_pow2(max(V,64)) compacted keys
  int P = 64;
  while (P < V) P <<= 1;
  const bool insort = tid < P;          // wave-uniform (P multiple of 64)

  u64 key = skey[tid];
  for (int k = 2; k <= P; k <<= 1) {
    for (int j = k >> 1; j > 0; j >>= 1) {
      const bool takeMin = (((tid & j) == 0) == ((tid & k) == 0));
      if (j >= 64) {                    // cross-wave via LDS (all hit barriers)
        if (insort) skey[tid] = key;
        __syncthreads();
        if (insort) {
          u64 other = skey[tid ^ j];
          const bool take = takeMin ? (other < key) : (other > key);
          key = take ? other : key;
        }
        __syncthreads();                // WAR for next stage
      } else if (insort) {              // in-wave via shfl_xor, no barriers
        u64 other = shfl_xor_u64(key, j);
        const bool take = takeMin ? (other < key) : (other > key);
        key = take ? other : key;
      }
    }
  }

  // ---- gather payload into sorted order (ws is L1/L2-hot)
  if (tid < V) {
    int orig = (int)(key & 0xFFFFFFFFull);
    float2 a = ws_aux[(size_t)b * PAD + orig];
    sbox[tid] = ws_box[(size_t)b * PAD + orig];
    ssc[tid]  = a.x;
    scls[tid] = (int)a.y;
  }
  __syncthreads();

  // ---- class-masked chunked greedy NMS (== sequential greedy exactly)
  bool   mykeep = tid < V;
  float4 jb = make_float4(0.f, 0.f, 0.f, 0.f);
  float  jarea = 0.f;
  int    jcls = -1;
  if (mykeep) {
    jb = sbox[tid];
    jcls = scls[tid];
    jarea = (jb.z - jb.x) * (jb.w - jb.y);
  }

  int kc = 0;
  const int nchunks = (V + 63) >> 6;
  for (int c = 0; c < nchunks; ++c) {
    // clear + build class->leader-lane masks (alive-so-far leaders only)
    if (tid < NCLS) cmask[tid] = 0ull;
    __syncthreads();
    if (wv == c && mykeep) atomicOr(&cmask[jcls], 1ull << (unsigned)lane);
    __syncthreads();

    // jsup bit l: chunk leader l (same class, if kept) suppresses me
    u64 jsup = 0ull;
    if (mykeep && wv >= c) {
      u64 m = cmask[jcls];
      if (wv == c) m &= (1ull << (unsigned)lane) - 1ull;   // only earlier lanes
      const int cb = c << 6;
      while (m) {
        int l = __ffsll((long long)m) - 1;
        m &= m - 1;
        float4 lb = sbox[cb + l];
        float la = (lb.z - lb.x) * (lb.w - lb.y);
        float iy1 = fmaxf(lb.x, jb.x), ix1 = fmaxf(lb.y, jb.y);
        float iy2 = fminf(lb.z, jb.z), ix2 = fminf(lb.w, jb.w);
        float inter = fmaxf(iy2 - iy1, 0.f) * fmaxf(ix2 - ix1, 0.f);
        if (inter > NMS_THR * fmaxf(la + jarea - inter, 1e-10f))
          jsup |= (1ull << (unsigned)l);
      }
    }

    if (wv == c) {                      // greedy resolve over set bits only
      u64 aliveW = __ballot(mykeep);
      u64 rem = aliveW;
      while (rem) {
        int l = __ffsll((long long)rem) - 1;
        rem &= ~(1ull << (unsigned)l);
        u64 kill = __ballot((int)((jsup >> (unsigned)l) & 1ull));
        aliveW &= ~kill;                // jsup bits only at lanes > l here
        rem    &= ~kill;
      }
      mykeep = ((aliveW >> (unsigned)lane) & 1ull) != 0;
      if (lane == 0) s_alive = aliveW;
    }
    __syncthreads();
    const u64 alive = s_alive;
    if (wv > c && (jsup & alive)) mykeep = false;
    kc += (int)__popcll(alive);
    // Output = first MAXI kept in sorted order; once MAXI are finalized,
    // later suppressions cannot change the output (== full NMS + top_k).
    if (kc >= MAXI) break;
  }

  // ---- ballot-scan compaction + emit.
  // Stale mykeep=1 threads (unprocessed chunks) get slot >= kc >= MAXI.
  u64 bm = __ballot((int)mykeep);
  if (lane == 0) wcnt[wv] = (int)__popcll(bm);
  __syncthreads();
  if (mykeep) {
    int base2 = 0;
    for (int q = 0; q < wv; ++q) base2 += wcnt[q];
    int slot = base2 + (int)__popcll(bm & ((1ull << (unsigned)lane) - 1ull));
    if (slot < MAXI) {
      float* o = out + ((size_t)b * MAXI + slot) * 6;
      o[0] = jb.x; o[1] = jb.y; o[2] = jb.z; o[3] = jb.w;
      o[4] = (float)jcls;
      o[5] = ssc[tid];
    }
  }
}

extern "C" void kernel_launch(void* const* d_in, const int* in_sizes, int n_in,
                              void* d_out, int out_size, void* d_ws, size_t ws_size,
                              hipStream_t stream) {
  const float* rois   = (const float*)d_in[0];
  const float* probs  = (const float*)d_in[1];
  const float* deltas = (const float*)d_in[2];
  const float* meta   = (const float*)d_in[3];
  float* out = (float*)d_out;

  const int nb = in_sizes[0] / (NROI * 4);       // = 8 images
  const int meta_stride = in_sizes[3] / nb;      // = 93 floats per image

  float4* ws_box = (float4*)d_ws;                              // nb*PAD*16 B
  float2* ws_aux = (float2*)((char*)d_ws + (size_t)nb * PAD * sizeof(float4));

  refine_kernel<<<nb * 16, 64, 0, stream>>>(rois, probs, deltas, meta,
                                            ws_box, ws_aux, meta_stride);
  sortnms_kernel<<<nb, BLK, 0, stream>>>(ws_box, ws_aux, out);
}